// Round 2
// baseline (69.425 us; speedup 1.0000x reference)
//
#include <hip/hip_runtime.h>

#define PH 7
#define PW 7
#define SCALE 0.0625f

// Problem constants (from setup_inputs): feature_map (1,128,56,56) fp32,
// rois_1/rois_2 (64,5) fp32, out (64,128,7,7) fp32.
#define NB 64
#define NC 128
#define FH 56
#define FW 56

__global__ __launch_bounds__(256) void DualMaskRoIPool_kernel(
    const float* __restrict__ feat,    // [C,H,W]
    const float* __restrict__ rois1,   // [B,5]
    const float* __restrict__ rois2,   // [B,5]
    float* __restrict__ out)           // [B,C,PH,PW]
{
    const int total = NB * NC * PH * PW;
    int tid = blockIdx.x * blockDim.x + threadIdx.x;
    if (tid >= total) return;

    int j = tid % PW;
    int i = (tid / PW) % PH;
    int c = (tid / (PW * PH)) % NC;
    int b = tid / (PW * PH * NC);
    // NC*PH*PW = 6272 is a multiple of 64 -> b is wave-uniform. Tell the
    // compiler so ROI loads become scalar loads and decode math is uniform.
    b = __builtin_amdgcn_readfirstlane(b);

    // ----- zoom both ROIs (round-half-even, clamp upper bound only) -----
    const float* r1 = rois1 + b * 5;
    const float* r2 = rois2 + b * 5;
    int x1a = (int)rintf(r1[1] * SCALE);
    int y1a = (int)rintf(r1[2] * SCALE);
    int x2a = (int)rintf(r1[3] * SCALE);
    int y2a = (int)rintf(r1[4] * SCALE);
    int x1b = (int)rintf(r2[1] * SCALE);
    int y1b = (int)rintf(r2[2] * SCALE);
    int x2b = (int)rintf(r2[3] * SCALE);
    int y2b = (int)rintf(r2[4] * SCALE);
    if (x1a >= FW) x1a = FW - 1;
    if (y1a >= FH) y1a = FH - 1;
    if (x2a >= FW) x2a = FW - 1;
    if (y2a >= FH) y2a = FH - 1;
    if (x1b >= FW) x1b = FW - 1;
    if (y1b >= FH) y1b = FH - 1;
    if (x2b >= FW) x2b = FW - 1;
    if (y2b >= FH) y2b = FH - 1;

    // ----- union box -----
    int ux1 = min(x1a, x1b);
    int uy1 = min(y1a, y1b);
    int ux2 = max(x2a, x2b);
    int uy2 = max(y2a, y2b);
    int h = uy2 - uy1 + 1;   // >= 1
    int w = ux2 - ux1 + 1;   // >= 1

    // ----- adaptive bin bounds (abs coords, [start, end)) -----
    int rs = uy1 + (i * h) / PH;
    int re = uy1 + ((i + 1) * h + PH - 1) / PH;
    int cs = ux1 + (j * w) / PW;
    int ce = ux1 + ((j + 1) * w + PW - 1) / PW;

    const float* fc = feat + c * (FH * FW);
    float m = -1e30f;  // NEG init; bins never empty (h>=1 => re>rs)
    for (int y = rs; y < re; ++y) {
        bool iny1 = (y >= y1a) && (y <= y2a);
        bool iny2 = (y >= y1b) && (y <= y2b);
        const float* frow = fc + y * FW;
        for (int x = cs; x < ce; ++x) {
            bool in = (iny1 && (x >= x1a) && (x <= x2a)) ||
                      (iny2 && (x >= x1b) && (x <= x2b));
            float v = in ? frow[x] : 0.0f;   // dual-mask: 0 inside union, outside both ROIs
            m = fmaxf(m, v);
        }
    }
    out[tid] = m;
}

extern "C" void kernel_launch(void* const* d_in, const int* in_sizes, int n_in,
                              void* d_out, int out_size, void* d_ws, size_t ws_size,
                              hipStream_t stream) {
    const float* feat  = (const float*)d_in[0];
    const float* rois1 = (const float*)d_in[1];
    const float* rois2 = (const float*)d_in[2];
    float* out = (float*)d_out;

    const int total = NB * NC * PH * PW;             // 401408
    const int block = 256;
    const int grid = (total + block - 1) / block;    // 1568
    DualMaskRoIPool_kernel<<<grid, block, 0, stream>>>(feat, rois1, rois2, out);
}